// Round 7
// baseline (288.421 us; speedup 1.0000x reference)
//
#include <hip/hip_runtime.h>
#include <cmath>

#define B   64
#define NM  64
#define DM  6
#define FA  37
#define FB  6
#define NP  512
#define DP  12
#define FPD 480
#define HM  128
#define HP  128

typedef _Float16 half8 __attribute__((ext_vector_type(8)));
typedef float f32x4 __attribute__((ext_vector_type(4)));

// ---------------- ws layout ----------------
static const size_t OFF_FPP = 0;                                 // B*128 floats
static const size_t OFF_Z1  = OFF_FPP + (size_t)B*128;           // fp16 [32768][256] -> 4,194,304 floats
static const size_t OFF_Z2  = OFF_Z1  + (size_t)32768*256/2;     // fp16 [32768][128] -> 2,097,152 floats
static const size_t OFF_W16 = OFF_Z2  + (size_t)32768*128/2;     // fp16 weights
// fp16 sub-offsets (in _Float16 units, from OFF_W16)
#define W16_WT1   0          // Wp1^T K-blocked [15][14][16][32]  (n-pad 224)
#define W16_WT2   107520     // Wp2^T K-blocked [7][8][16][32]    (n-pad 128, k<224)
#define W16_WTOP  136192     // Wop^T K-blocked [4][8][16][32]    (k-pad 128)
#define W16_MW1T  152576     // [128][64]   mol W1^T  (k<43)  flat
#define W16_MW2T  160768     // [128][160]  mol W2^T  (k<134) flat
#define W16_MWOT  181248     // [128][160]  mol Wo^T  (k<134) flat
#define W16_BP1   201728     // [224] bp1 fp16 pad0
#define W16_BP2   201952     // [128] bp2 fp16 pad0
#define W16_TOT   202080
// ws total ~= 6.40M floats = 25.6 MB

__device__ __forceinline__ half8 cvt8(float4 f0, float4 f1) {
    half8 h;
    h[0] = (_Float16)f0.x; h[1] = (_Float16)f0.y; h[2] = (_Float16)f0.z; h[3] = (_Float16)f0.w;
    h[4] = (_Float16)f1.x; h[5] = (_Float16)f1.y; h[6] = (_Float16)f1.z; h[7] = (_Float16)f1.w;
    return h;
}

// ---------------- weight prep: transpose + pad + fp16 + K-blocked layouts ----------------
__global__ void k_prep(const float* __restrict__ Wp1, const float* __restrict__ Wp2,
                       const float* __restrict__ Wop,
                       const float* __restrict__ W1,  const float* __restrict__ W2,
                       const float* __restrict__ Wo,
                       const float* __restrict__ bp1, const float* __restrict__ bp2,
                       _Float16* __restrict__ w16) {
    int idx = blockIdx.x * 256 + threadIdx.x;
    if (idx < W16_WT2) {                         // Wt1 blocked [15][14][16][32]
        int c = idx / 7168, r = idx % 7168;
        int nt = r >> 9, lr = (r >> 5) & 15, kin = r & 31;
        int n = nt * 16 + lr, k = c * 32 + kin;
        w16[idx] = (n < 200) ? (_Float16)Wp1[k * 200 + n] : (_Float16)0.f;
    } else if (idx < W16_WTOP) {                 // Wt2 blocked [7][8][16][32]
        int r0 = idx - W16_WT2;
        int c = r0 >> 12, r = r0 & 4095;
        int nt = r >> 9, lr = (r >> 5) & 15, kin = r & 31;
        int n = nt * 16 + lr, k = c * 32 + kin;
        w16[idx] = (n < 100 && k < 200) ? (_Float16)Wp2[k * 100 + n] : (_Float16)0.f;
    } else if (idx < W16_MW1T) {                 // Wtop blocked [4][8][16][32]
        int r0 = idx - W16_WTOP;
        int c = r0 >> 12, r = r0 & 4095;
        int nt = r >> 9, lr = (r >> 5) & 15, kin = r & 31;
        int n = nt * 16 + lr, k = c * 32 + kin;
        w16[idx] = (k < 100) ? (_Float16)Wop[k * 128 + n] : (_Float16)0.f;
    } else if (idx < W16_MW2T) {                 // MW1t[n][k] = W1[k][n], k<43
        int r = idx - W16_MW1T;
        int n = r >> 6, k = r & 63;
        w16[idx] = (k < 43) ? (_Float16)W1[k * 128 + n] : (_Float16)0.f;
    } else if (idx < W16_MWOT) {                 // MW2t[n][k] = W2[k][n], k<134
        int r = idx - W16_MW2T;
        int n = r / 160, k = r % 160;
        w16[idx] = (k < 134) ? (_Float16)W2[k * 128 + n] : (_Float16)0.f;
    } else if (idx < W16_BP1) {                  // MWot[n][k] = Wo[k][n], k<134
        int r = idx - W16_MWOT;
        int n = r / 160, k = r % 160;
        w16[idx] = (k < 134) ? (_Float16)Wo[k * 128 + n] : (_Float16)0.f;
    } else if (idx < W16_BP2) {
        int k = idx - W16_BP1;
        w16[idx] = (k < 200) ? (_Float16)bp1[k] : (_Float16)0.f;
    } else if (idx < W16_TOT) {
        int k = idx - W16_BP2;
        w16[idx] = (k < 100) ? (_Float16)bp2[k] : (_Float16)0.f;
    }
}

// ---------------- MFMA GEMM 1: Z1(fp16,[.][256]) = p_atoms @ Wp1 ----------------
// 4 waves = 2 rw x 2 cw; wave-tile 16x112; block 32 rows; grid 1024; A reg-prefetched
__global__ __launch_bounds__(256) void k_zp1(
        const float* __restrict__ A, const _Float16* __restrict__ Wt,
        _Float16* __restrict__ Z) {
    int tid = threadIdx.x, lane = tid & 63, wid = tid >> 6;
    int rw = wid & 1, cw = wid >> 1;
    int rbase = blockIdx.x * 32 + rw * 16;
    int lr = lane & 15, q = lane >> 4;
    f32x4 acc[7] = {};
    const float* Ar = A + (size_t)(rbase + lr) * FPD + q * 8;
    const _Float16* Wb = Wt + (size_t)(cw * 7) * 512 + lr * 32 + q * 8;
    float4 a0 = *(const float4*)(Ar);
    float4 a1 = *(const float4*)(Ar + 4);
    for (int c = 0; c < 15; ++c) {
        int cn = (c < 14) ? c + 1 : 14;           // harmless re-load on last iter
        float4 na0 = *(const float4*)(Ar + cn * 32);
        float4 na1 = *(const float4*)(Ar + cn * 32 + 4);
        half8 a = cvt8(a0, a1);
        const _Float16* wc = Wb + (size_t)c * 7168; // c*14*512
        #pragma unroll
        for (int nt = 0; nt < 7; ++nt) {
            half8 b = *(const half8*)(wc + nt * 512);
            acc[nt] = __builtin_amdgcn_mfma_f32_16x16x32_f16(a, b, acc[nt], 0, 0, 0);
        }
        a0 = na0; a1 = na1;
    }
    int rj = q * 4, cbase = cw * 112;
    #pragma unroll
    for (int nt = 0; nt < 7; ++nt) {
        int col = cbase + nt * 16 + lr;           // [0,224); cols [224,256) never read
        #pragma unroll
        for (int j = 0; j < 4; ++j)
            Z[(size_t)(rbase + rj + j) * 256 + col] = (_Float16)acc[nt][j];
    }
}

// ---------------- fused gather+GEMM 2: Z2(fp16) = relu(gather(Z1)+bp1) @ Wp2 -------
// 4 waves = 2 rw x 2 cw; wave-tile 16x64; block 32 rows x 128 cols; grid 1024 XCD-chunked
__global__ __launch_bounds__(256) void k_zp2f(
        const _Float16* __restrict__ Z1, const int* __restrict__ edges,
        const _Float16* __restrict__ bp1h, const _Float16* __restrict__ Wt,
        _Float16* __restrict__ Z2) {
    int bid = blockIdx.x;
    int t = (bid & 7) * 128 + (bid >> 3);         // 32-row tiles, molecules chunked per XCD
    int tid = threadIdx.x, lane = tid & 63, wid = tid >> 6;
    int rw = wid & 1, cw = wid >> 1;
    int lr = lane & 15, q = lane >> 4;
    int rbase = t * 32 + rw * 16;
    int gr = rbase + lr;
    int mb = gr >> 9, lrow = gr & 511;
    const int* ep = edges + (size_t)gr * DP;
    const _Float16* zb = Z1 + (((size_t)mb << 9) << 8);   // mb*512*256
    const _Float16* src[13];
    src[0] = zb + ((size_t)lrow << 8) + q * 8;
    #pragma unroll
    for (int d = 0; d < 12; ++d) src[d + 1] = zb + ((size_t)ep[d] << 8) + q * 8;

    f32x4 acc[4] = {};
    for (int c = 0; c < 7; ++c) {
        int ko = c * 32;
        half8 t0  = *(const half8*)(src[0]  + ko);
        half8 t1  = *(const half8*)(src[1]  + ko);
        half8 t2  = *(const half8*)(src[2]  + ko);
        half8 t3  = *(const half8*)(src[3]  + ko);
        half8 t4  = *(const half8*)(src[4]  + ko);
        half8 t5  = *(const half8*)(src[5]  + ko);
        half8 t6  = *(const half8*)(src[6]  + ko);
        half8 t7  = *(const half8*)(src[7]  + ko);
        half8 t8  = *(const half8*)(src[8]  + ko);
        half8 t9  = *(const half8*)(src[9]  + ko);
        half8 t10 = *(const half8*)(src[10] + ko);
        half8 t11 = *(const half8*)(src[11] + ko);
        half8 t12 = *(const half8*)(src[12] + ko);
        half8 bb  = *(const half8*)(bp1h + ko + q * 8);
        half8 s = (((t0 + t1) + (t2 + t3)) + ((t4 + t5) + (t6 + t7)))
                + (((t8 + t9) + (t10 + t11)) + (t12 + bb));
        #pragma unroll
        for (int j = 0; j < 8; ++j) if (s[j] < (_Float16)0.f) s[j] = (_Float16)0.f;
        const _Float16* wc = Wt + (size_t)(c * 8 + cw * 4) * 512 + lr * 32 + q * 8;
        #pragma unroll
        for (int nt = 0; nt < 4; ++nt) {
            half8 b = *(const half8*)(wc + nt * 512);
            acc[nt] = __builtin_amdgcn_mfma_f32_16x16x32_f16(s, b, acc[nt], 0, 0, 0);
        }
    }
    int rj = q * 4, cbase = cw * 64;
    #pragma unroll
    for (int nt = 0; nt < 4; ++nt) {
        int col = cbase + nt * 16 + lr;           // [0,128); pad cols get 0 via zero W rows
        #pragma unroll
        for (int j = 0; j < 4; ++j)
            Z2[(size_t)(rbase + rj + j) * 128 + col] = (_Float16)acc[nt][j];
    }
}

// ---------------- fused gather+GraphOutput: fpp += colsum tanh(relu(gather(Z2)+bp2)@Wop+bop)
// 4 waves = 2 rw x 2 cw; wave-tile 16x64; block 32 rows; grid 1024 XCD-chunked
__global__ __launch_bounds__(256) void k_pof(
        const _Float16* __restrict__ Z2, const int* __restrict__ edges,
        const _Float16* __restrict__ bp2h, const _Float16* __restrict__ Wt,
        const float* __restrict__ bop, float* __restrict__ fpp) {
    int bid = blockIdx.x;
    int t = (bid & 7) * 128 + (bid >> 3);
    int tid = threadIdx.x, lane = tid & 63, wid = tid >> 6;
    int rw = wid & 1, cw = wid >> 1;
    int lr = lane & 15, q = lane >> 4;
    int rbase = t * 32 + rw * 16;
    int gr = rbase + lr;
    int mb = gr >> 9, lrow = gr & 511;
    const int* ep = edges + (size_t)gr * DP;
    const _Float16* zb = Z2 + (((size_t)mb << 9) << 7);   // mb*512*128
    const _Float16* src[13];
    src[0] = zb + ((size_t)lrow << 7) + q * 8;
    #pragma unroll
    for (int d = 0; d < 12; ++d) src[d + 1] = zb + ((size_t)ep[d] << 7) + q * 8;

    f32x4 acc[4] = {};
    for (int c = 0; c < 4; ++c) {
        int ko = c * 32;
        half8 t0  = *(const half8*)(src[0]  + ko);
        half8 t1  = *(const half8*)(src[1]  + ko);
        half8 t2  = *(const half8*)(src[2]  + ko);
        half8 t3  = *(const half8*)(src[3]  + ko);
        half8 t4  = *(const half8*)(src[4]  + ko);
        half8 t5  = *(const half8*)(src[5]  + ko);
        half8 t6  = *(const half8*)(src[6]  + ko);
        half8 t7  = *(const half8*)(src[7]  + ko);
        half8 t8  = *(const half8*)(src[8]  + ko);
        half8 t9  = *(const half8*)(src[9]  + ko);
        half8 t10 = *(const half8*)(src[10] + ko);
        half8 t11 = *(const half8*)(src[11] + ko);
        half8 t12 = *(const half8*)(src[12] + ko);
        half8 bb  = *(const half8*)(bp2h + ko + q * 8);
        half8 s = (((t0 + t1) + (t2 + t3)) + ((t4 + t5) + (t6 + t7)))
                + (((t8 + t9) + (t10 + t11)) + (t12 + bb));
        #pragma unroll
        for (int j = 0; j < 8; ++j) if (s[j] < (_Float16)0.f) s[j] = (_Float16)0.f;
        const _Float16* wc = Wt + (size_t)(c * 8 + cw * 4) * 512 + lr * 32 + q * 8;
        #pragma unroll
        for (int nt = 0; nt < 4; ++nt) {
            half8 b = *(const half8*)(wc + nt * 512);
            acc[nt] = __builtin_amdgcn_mfma_f32_16x16x32_f16(s, b, acc[nt], 0, 0, 0);
        }
    }
    int cbase = cw * 64;
    #pragma unroll
    for (int nt = 0; nt < 4; ++nt) {
        int col = cbase + nt * 16 + lr;
        float bb = bop[col];
        float s = 0.f;
        #pragma unroll
        for (int j = 0; j < 4; ++j) s += tanhf(acc[nt][j] + bb);
        s += __shfl_xor(s, 16);
        s += __shfl_xor(s, 32);                  // sum over the wave's 16 rows
        if (lane < 16) atomicAdd(&fpp[mb * 128 + col], s);
    }
}

// ---------------- FUSED molecule path + FC: one block per molecule ----------------
#define P_ATOM 40
#define P_S1   72
#define P_A    136
#define P_S23  168
__global__ __launch_bounds__(512) void k_mol(
        const float* __restrict__ m_atoms, const float* __restrict__ m_bonds,
        const int* __restrict__ m_edges,
        const _Float16* __restrict__ W1t, const _Float16* __restrict__ W2t,
        const _Float16* __restrict__ Wot,
        const float* __restrict__ b1, const float* __restrict__ b2,
        const float* __restrict__ bo,
        const float* __restrict__ fpp,
        const float* __restrict__ Wf1, const float* __restrict__ bf1,
        const float* __restrict__ Wf2, const float* __restrict__ bf2,
        const float* __restrict__ Wout, const float* __restrict__ bout,
        float* __restrict__ out) {
    int b = blockIdx.x, tid = threadIdx.x;
    __shared__ __align__(16) float smem[11464];
    float*     atoms_sh = smem;                        // [64][40] fp32
    _Float16*  a1  = (_Float16*)smem;                  // [64][136] fp16 (after atoms dead)
    _Float16*  S1  = (_Float16*)(smem + 4352);         // [64][72] fp16
    _Float16*  S23 = (_Float16*)(smem + 4352);         // [64][168] fp16 (after S1 dead)
    float*     bond  = smem + 9728;                    // [64][6]
    int*       edg   = (int*)(smem + 10112);           // [64][6]
    float*     red   = smem + 10496;                   // [4][128]
    float*     fcb   = smem + 11008;                   // fp[256] h1[100] h2[100]

    const float* ga = m_atoms + (size_t)b * NM * FA;
    for (int i = tid; i < NM * FA; i += 512)
        atoms_sh[(i / FA) * P_ATOM + (i % FA)] = ga[i];
    if (tid < NM * DM) edg[tid] = m_edges[b * NM * DM + tid];
    if (tid < NM * FB) {
        int r = tid / FB, j = tid % FB;
        float s = 0.f;
        #pragma unroll
        for (int d = 0; d < DM; ++d) s += m_bonds[((size_t)(b * NM + r) * DM + d) * FB + j];
        bond[tid] = s;
    }
    __syncthreads();

    for (int i = tid; i < 64 * 64; i += 512) {
        int r = i >> 6, k = i & 63;
        float v = 0.f;
        if (k < FA) {
            v = atoms_sh[r * P_ATOM + k];
            #pragma unroll
            for (int d = 0; d < DM; ++d) v += atoms_sh[edg[r * DM + d] * P_ATOM + k];
        } else if (k < FA + FB) {
            v = bond[r * FB + (k - FA)];
        }
        S1[r * P_S1 + k] = (_Float16)v;
    }
    __syncthreads();

    int lane = tid & 63, wid = tid >> 6;
    int rw = wid & 3, cw = wid >> 2;
    int rbase = rw * 16, cbase = cw * 64;
    int lr = lane & 15, lkb = (lane >> 4) * 8, rj = (lane >> 4) * 4;

    {   // L1: a1 = relu(S1 @ W1t + b1)
        f32x4 acc[4] = {};
        for (int k0 = 0; k0 < 64; k0 += 32) {
            half8 a = *(const half8*)&S1[(rbase + lr) * P_S1 + k0 + lkb];
            #pragma unroll
            for (int nt = 0; nt < 4; ++nt) {
                half8 bf = *(const half8*)&W1t[(cbase + nt * 16 + lr) * 64 + k0 + lkb];
                acc[nt] = __builtin_amdgcn_mfma_f32_16x16x32_f16(a, bf, acc[nt], 0, 0, 0);
            }
        }
        #pragma unroll
        for (int nt = 0; nt < 4; ++nt) {
            int col = cbase + nt * 16 + lr;
            float bb = b1[col];
            #pragma unroll
            for (int j = 0; j < 4; ++j)
                a1[(rbase + rj + j) * P_A + col] = (_Float16)fmaxf(acc[nt][j] + bb, 0.f);
        }
    }
    __syncthreads();

    for (int i = tid; i < 64 * 160; i += 512) {
        int r = i / 160, k = i % 160;
        float v = 0.f;
        if (k < 128) {
            v = (float)a1[r * P_A + k];
            #pragma unroll
            for (int d = 0; d < DM; ++d) v += (float)a1[edg[r * DM + d] * P_A + k];
        } else if (k < 134) {
            v = bond[r * FB + (k - 128)];
        }
        S23[r * P_S23 + k] = (_Float16)v;
    }
    __syncthreads();

    f32x4 acc2[4] = {};
    for (int k0 = 0; k0 < 160; k0 += 32) {
        half8 a = *(const half8*)&S23[(rbase + lr) * P_S23 + k0 + lkb];
        #pragma unroll
        for (int nt = 0; nt < 4; ++nt) {
            half8 bf = *(const half8*)&W2t[(cbase + nt * 16 + lr) * 160 + k0 + lkb];
            acc2[nt] = __builtin_amdgcn_mfma_f32_16x16x32_f16(a, bf, acc2[nt], 0, 0, 0);
        }
    }
    __syncthreads();

    #pragma unroll
    for (int nt = 0; nt < 4; ++nt) {
        int col = cbase + nt * 16 + lr;
        float bb = b2[col];
        #pragma unroll
        for (int j = 0; j < 4; ++j)
            S23[(rbase + rj + j) * P_S23 + col] = (_Float16)fmaxf(acc2[nt][j] + bb, 0.f);
    }
    for (int i = tid; i < 64 * 32; i += 512) {
        int r = i >> 5, k = 128 + (i & 31);
        S23[r * P_S23 + k] = (k < 134) ? (_Float16)bond[r * FB + (k - 128)] : (_Float16)0.f;
    }
    __syncthreads();

    {   // L3: fpm = sum_rows tanh(S3 @ Wot + bo)
        f32x4 acc3[4] = {};
        for (int k0 = 0; k0 < 160; k0 += 32) {
            half8 a = *(const half8*)&S23[(rbase + lr) * P_S23 + k0 + lkb];
            #pragma unroll
            for (int nt = 0; nt < 4; ++nt) {
                half8 bf = *(const half8*)&Wot[(cbase + nt * 16 + lr) * 160 + k0 + lkb];
                acc3[nt] = __builtin_amdgcn_mfma_f32_16x16x32_f16(a, bf, acc3[nt], 0, 0, 0);
            }
        }
        #pragma unroll
        for (int nt = 0; nt < 4; ++nt) {
            int col = cbase + nt * 16 + lr;
            float bb = bo[col];
            float s = 0.f;
            #pragma unroll
            for (int j = 0; j < 4; ++j) s += tanhf(acc3[nt][j] + bb);
            s += __shfl_xor(s, 16);
            s += __shfl_xor(s, 32);
            if (lane < 16) red[rw * 128 + col] = s;
        }
    }
    __syncthreads();

    if (tid < 128)       fcb[tid] = red[tid] + red[128 + tid] + red[256 + tid] + red[384 + tid];
    else if (tid < 256)  fcb[tid] = fpp[b * 128 + (tid - 128)];
    __syncthreads();
    if (tid < 100) {
        float acc = bf1[tid];
        for (int k = 0; k < 256; ++k) acc = fmaf(fcb[k], Wf1[k * 100 + tid], acc);
        fcb[256 + tid] = acc;
    }
    __syncthreads();
    if (tid < 100) {
        float acc = bf2[tid];
        for (int k = 0; k < 100; ++k) acc = fmaf(fcb[256 + k], Wf2[k * 100 + tid], acc);
        fcb[356 + tid] = acc;
    }
    __syncthreads();
    if (tid < 64) {
        float v = fcb[356 + tid] * Wout[tid];
        if (tid + 64 < 100) v += fcb[356 + tid + 64] * Wout[tid + 64];
        #pragma unroll
        for (int off = 32; off > 0; off >>= 1) v += __shfl_down(v, off);
        if (tid == 0) out[b] = 1.f / (1.f + expf(-(v + bout[0])));
    }
}

extern "C" void kernel_launch(void* const* d_in, const int* in_sizes, int n_in,
                              void* d_out, int out_size, void* d_ws, size_t ws_size,
                              hipStream_t stream) {
    const float* m_atoms = (const float*)d_in[0];
    const float* m_bonds = (const float*)d_in[1];
    const int*   m_edges = (const int*)  d_in[2];
    const float* p_atoms = (const float*)d_in[3];
    const int*   p_edges = (const int*)  d_in[4];
    const float* W1   = (const float*)d_in[5];  const float* b1   = (const float*)d_in[6];
    const float* W2   = (const float*)d_in[7];  const float* b2   = (const float*)d_in[8];
    const float* Wp1  = (const float*)d_in[9];  const float* bp1  = (const float*)d_in[10];
    const float* Wp2  = (const float*)d_in[11]; const float* bp2  = (const float*)d_in[12];
    const float* Wo   = (const float*)d_in[13]; const float* bo   = (const float*)d_in[14];
    const float* Wop  = (const float*)d_in[15]; const float* bop  = (const float*)d_in[16];
    const float* Wf1  = (const float*)d_in[17]; const float* bf1  = (const float*)d_in[18];
    const float* Wf2  = (const float*)d_in[19]; const float* bf2  = (const float*)d_in[20];
    const float* Wout = (const float*)d_in[21]; const float* bout = (const float*)d_in[22];

    float* ws   = (float*)d_ws;
    float* fpp  = ws + OFF_FPP;
    _Float16* z1  = (_Float16*)(ws + OFF_Z1);
    _Float16* z2  = (_Float16*)(ws + OFF_Z2);
    _Float16* w16 = (_Float16*)(ws + OFF_W16);

    hipMemsetAsync(fpp, 0, (size_t)B * 128 * sizeof(float), stream);
    k_prep<<<dim3((W16_TOT + 255) / 256), 256, 0, stream>>>(
        Wp1, Wp2, Wop, W1, W2, Wo, bp1, bp2, w16);

    k_zp1 <<<dim3(B * NP / 32), 256, 0, stream>>>(p_atoms, w16 + W16_WT1, z1);
    k_zp2f<<<dim3(B * NP / 32), 256, 0, stream>>>(z1, p_edges, w16 + W16_BP1,
                                                  w16 + W16_WT2, z2);
    k_pof <<<dim3(B * NP / 32), 256, 0, stream>>>(z2, p_edges, w16 + W16_BP2,
                                                  w16 + W16_WTOP, bop, fpp);

    k_mol <<<dim3(B), 512, 0, stream>>>(m_atoms, m_bonds, m_edges,
                                        w16 + W16_MW1T, w16 + W16_MW2T, w16 + W16_MWOT,
                                        b1, b2, bo, fpp,
                                        Wf1, bf1, Wf2, bf2, Wout, bout, (float*)d_out);
}